// Round 4
// baseline (145.462 us; speedup 1.0000x reference)
//
#include <hip/hip_runtime.h>

// P2M loss. B=2, M=8192, V={642,2562,10242}, E={1920,7680,30720}
// 2 kernels: kMega (chamfer mins via device atomicMin + lap/move partials),
//            kFinal (combine + lap-sum + edge/normal + ticketed output).
// ws layout (bytes):
//   0      : float acc            (memset 0)
//   4      : uint  ticket         (memset 0)
//   8      : float lapPartials[128]          (written unconditionally)
//   1024   : u64 minsA0[13446]   b=0 per-vertex packed (ford(d)<<32)|argmin_m
//   108592 : u32 minsA1[13446]   b=1 per-vertex ford(d)
//   162376 : u32 minsB [49152]   per-gt ford(d), slot = lvl*16384+b*8192+m
//   (mins memset 0xFF = +inf in ordered encoding; end 358984)

#define DEV __device__ __forceinline__

#define OFF_LAP  8
#define OFF_MA0  1024
#define OFF_MA1  108592
#define OFF_MB   162376
#define MINS_END 358984

DEV unsigned ford(float f) {
    unsigned u = __float_as_uint(f);
    return (u & 0x80000000u) ? ~u : (u | 0x80000000u);
}
DEV float funord(unsigned o) {
    unsigned u = (o & 0x80000000u) ? (o ^ 0x80000000u) : ~o;
    return __uint_as_float(u);
}
DEV unsigned long long umin64(unsigned long long a, unsigned long long b) { return a < b ? a : b; }

DEV float blockReduceSum256(float v) {
    #pragma unroll
    for (int o = 32; o > 0; o >>= 1) v += __shfl_down(v, o, 64);
    __shared__ float red4[4];
    int wid = threadIdx.x >> 6;
    if ((threadIdx.x & 63) == 0) red4[wid] = v;
    __syncthreads();
    return (threadIdx.x == 0) ? (red4[0] + red4[1] + red4[2] + red4[3]) : 0.0f;
}

// ---------- role A: per-vertex min over a 256-gt chunk, R=14 verts/lane, 4-wave split of chunk
// a in [0,512): vtG = a>>5 (16 tiles: L0 1, L1 3, L2 12), mc = a&31 (256-gt chunks)
template<bool ARGMIN>
DEV void roleA(int a, const float* p0, const float* p1, const float* p2,
               const float* gt, char* ws, char* smem)
{
    const int b = ARGMIN ? 0 : 1;
    int vtG = a >> 5, mc = a & 31;
    int vtL, V, lvlOff; const float* predL;
    if (vtG == 0)     { vtL = 0;       V = 642;   predL = p0; lvlOff = 0; }
    else if (vtG < 4) { vtL = vtG - 1; V = 2562;  predL = p1; lvlOff = 642; }
    else              { vtL = vtG - 4; V = 10242; predL = p2; lvlOff = 3204; }
    int tid = threadIdx.x, lane = tid & 63, w = tid >> 6;
    float4* SG = (float4*)smem;
    int mbase = mc << 8;
    {   // stage 256 gt points, pre-scaled by -2, w = |g|^2
        const float* gp = gt + ((size_t)(b * 8192 + mbase + tid)) * 3;
        float gx = gp[0], gy = gp[1], gz = gp[2];
        SG[tid] = make_float4(-2.f * gx, -2.f * gy, -2.f * gz,
                              fmaf(gx, gx, fmaf(gy, gy, gz * gz)));
    }
    float px[14], py[14], pz[14];
    #pragma unroll
    for (int r = 0; r < 14; r++) {
        int vr = vtL * 896 + r * 64 + lane;
        int v = vr - (vr >= V ? V : 0);          // wrapped duplicates produce identical keys
        const float* pp = predL + ((size_t)(b * V + v)) * 3;
        px[r] = pp[0]; py[r] = pp[1]; pz[r] = pp[2];
    }
    __syncthreads();
    if (ARGMIN) {
        float best[14]; int bi[14];
        #pragma unroll
        for (int r = 0; r < 14; r++) { best[r] = 3.0e38f; bi[r] = 0; }
        #pragma unroll 4
        for (int i = 0; i < 64; i++) {
            int j = (w << 6) + i;
            float4 q = SG[j];                    // wave-uniform -> LDS broadcast
            int cand = mbase + j;
            #pragma unroll
            for (int r = 0; r < 14; r++) {
                float d = fmaf(q.x, px[r], fmaf(q.y, py[r], fmaf(q.z, pz[r], q.w)));
                if (d < best[r]) { best[r] = d; bi[r] = cand; }
            }
        }
        __syncthreads();                          // staged data dead; reuse LDS for RED
        unsigned long long* RED = (unsigned long long*)smem;
        #pragma unroll
        for (int r = 0; r < 14; r++)
            RED[w * 896 + r * 64 + lane] = ((unsigned long long)ford(best[r]) << 32) | (unsigned)bi[r];
        __syncthreads();
        unsigned long long* MA0 = (unsigned long long*)(ws + OFF_MA0);
        for (int s = tid; s < 896; s += 256) {
            unsigned long long mm = umin64(umin64(RED[s], RED[s + 896]),
                                           umin64(RED[s + 1792], RED[s + 2688]));
            int vr = vtL * 896 + s; int v = vr - (vr >= V ? V : 0);
            atomicMin(&MA0[lvlOff + v], mm);
        }
    } else {
        float best[14];
        #pragma unroll
        for (int r = 0; r < 14; r++) best[r] = 3.0e38f;
        #pragma unroll 2
        for (int i = 0; i < 64; i += 2) {
            int j = (w << 6) + i;
            float4 q0 = SG[j], q1 = SG[j + 1];
            #pragma unroll
            for (int r = 0; r < 14; r++) {
                float d0 = fmaf(q0.x, px[r], fmaf(q0.y, py[r], fmaf(q0.z, pz[r], q0.w)));
                float d1 = fmaf(q1.x, px[r], fmaf(q1.y, py[r], fmaf(q1.z, pz[r], q1.w)));
                best[r] = fminf(best[r], fminf(d0, d1));      // v_min3_f32
            }
        }
        __syncthreads();
        unsigned* RED = (unsigned*)smem;
        #pragma unroll
        for (int r = 0; r < 14; r++)
            RED[w * 896 + r * 64 + lane] = ford(best[r]);
        __syncthreads();
        unsigned* MA1 = (unsigned*)(ws + OFF_MA1);
        for (int s = tid; s < 896; s += 256) {
            unsigned mm = min(min(RED[s], RED[s + 896]), min(RED[s + 1792], RED[s + 2688]));
            int vr = vtL * 896 + s; int v = vr - (vr >= V ? V : 0);
            atomicMin(&MA1[lvlOff + v], mm);
        }
    }
}

// ---------- role B: per-gt min over a 256-vert chunk, R=16 gt/lane, 4-wave split of chunk
// i in [0,880): c55 = i%55 (chunks: L0 3, L1 11, L2 41), rest: mt (8), b (2)
DEV void roleB(int i, const float* p0, const float* p1, const float* p2,
               const float* gt, char* ws, char* smem)
{
    int c55 = i % 55; int rest = i / 55; int mt = rest & 7; int b = rest >> 3;
    int lvl, c, V; const float* predL;
    if (c55 < 3)       { lvl = 0; c = c55;      V = 642;   predL = p0; }
    else if (c55 < 14) { lvl = 1; c = c55 - 3;  V = 2562;  predL = p1; }
    else               { lvl = 2; c = c55 - 14; V = 10242; predL = p2; }
    int tid = threadIdx.x, lane = tid & 63, w = tid >> 6;
    float4* SP = (float4*)smem;
    int vbase = c << 8;
    {
        int v = vbase + tid;
        if (v < V) {
            const float* pp = predL + ((size_t)(b * V + v)) * 3;
            float x = pp[0], y = pp[1], z = pp[2];
            SP[tid] = make_float4(-2.f * x, -2.f * y, -2.f * z,
                                  fmaf(x, x, fmaf(y, y, z * z)));
        } else SP[tid] = make_float4(0.f, 0.f, 0.f, 3.0e38f);   // sentinel
    }
    float gx[16], gy[16], gz[16];
    #pragma unroll
    for (int r = 0; r < 16; r++) {
        int m = (mt << 10) + r * 64 + lane;
        const float* gp = gt + ((size_t)(b * 8192 + m)) * 3;
        gx[r] = gp[0]; gy[r] = gp[1]; gz[r] = gp[2];
    }
    __syncthreads();
    float best[16];
    #pragma unroll
    for (int r = 0; r < 16; r++) best[r] = 3.0e38f;
    #pragma unroll 2
    for (int i2 = 0; i2 < 64; i2 += 2) {
        int j = (w << 6) + i2;
        float4 q0 = SP[j], q1 = SP[j + 1];
        #pragma unroll
        for (int r = 0; r < 16; r++) {
            float d0 = fmaf(q0.x, gx[r], fmaf(q0.y, gy[r], fmaf(q0.z, gz[r], q0.w)));
            float d1 = fmaf(q1.x, gx[r], fmaf(q1.y, gy[r], fmaf(q1.z, gz[r], q1.w)));
            best[r] = fminf(best[r], fminf(d0, d1));
        }
    }
    __syncthreads();
    unsigned* RED = (unsigned*)smem;                // 16 KB
    #pragma unroll
    for (int r = 0; r < 16; r++)
        RED[(w << 10) + r * 64 + lane] = ford(best[r]);
    __syncthreads();
    unsigned* MB = (unsigned*)(ws + OFF_MB);
    for (int s = tid; s < 1024; s += 256) {
        unsigned mm = min(min(RED[s], RED[s + 1024]), min(RED[s + 2048], RED[s + 3072]));
        atomicMin(&MB[(lvl << 14) + (b << 13) + (mt << 10) + s], mm);
    }
}

// ---------- mega: lap [0,128) | B [128,1008) | A-b0 [1008,1520) | A-b1 [1520,2032)
__global__ __launch_bounds__(256, 4) void kMega(
    const float* __restrict__ p0, const float* __restrict__ p1, const float* __restrict__ p2,
    const float* __restrict__ b0p, const float* __restrict__ b1p, const float* __restrict__ b2p,
    const int* __restrict__ l0, const int* __restrict__ l1, const int* __restrict__ l2,
    const float* __restrict__ gt, char* ws)
{
    extern __shared__ char smem[];
    int bid = blockIdx.x;
    if (bid < 128) {
        float c = 0.0f;
        int idx = bid * 256 + threadIdx.x;
        if (idx < 26892) {
            int level, V, t;
            const float *pred, *bef; const int* lap;
            if (idx < 1284)      { level = 0; V = 642;   pred = p0; bef = b0p; lap = l0; t = idx; }
            else if (idx < 6408) { level = 1; V = 2562;  pred = p1; bef = b1p; lap = l1; t = idx - 1284; }
            else                 { level = 2; V = 10242; pred = p2; bef = b2p; lap = l2; t = idx - 6408; }
            int b = t / V;
            int v = t - b * V;
            const float* P  = pred + ((size_t)b * V + v) * 3;
            const float* Bf = bef  + ((size_t)b * V + v) * 3;
            float dx = Bf[0] - P[0], dy = Bf[1] - P[1], dz = Bf[2] - P[2];
            float sx = 0.f, sy = 0.f, sz = 0.f;
            const int* L = lap + v * 10;
            #pragma unroll
            for (int j = 0; j < 8; j++) {
                int n = L[j];
                if (n >= 0) {
                    const float* Pn = pred + ((size_t)b * V + n) * 3;
                    const float* Bn = bef  + ((size_t)b * V + n) * 3;
                    sx += Bn[0] - Pn[0]; sy += Bn[1] - Pn[1]; sz += Bn[2] - Pn[2];
                }
            }
            float invc = 1.0f / (float)L[9];
            float lx = dx - sx * invc, ly = dy - sy * invc, lz = dz - sz * invc;
            float sl = fmaf(lx, lx, fmaf(ly, ly, lz * lz));
            float sm = fmaf(dx, dx, fmaf(dy, dy, dz * dz));
            float lapc = (level == 0) ? 0.2f : 1.0f;
            float iBV = 1.0f / (2.0f * (float)V);
            c = sl * (0.5f * lapc * iBV) + ((level > 0) ? sm * (0.1f * lapc * iBV) : 0.0f);
        }
        c = blockReduceSum256(c);
        if (threadIdx.x == 0) ((float*)(ws + OFF_LAP))[bid] = c;
    }
    else if (bid < 1008) roleB(bid - 128, p0, p1, p2, gt, ws, smem);
    else if (bid < 1520) roleA<true >(bid - 1008, p0, p1, p2, gt, ws, smem);
    else                 roleA<false>(bid - 1520, p0, p1, p2, gt, ws, smem);
}

// ---------- final: chamfer sums [0,298) | lap-sum 298 | edge+normal [299,614) ----------
__global__ __launch_bounds__(256) void kFinal(
    const float* __restrict__ p0, const float* __restrict__ p1, const float* __restrict__ p2,
    const int* __restrict__ e0p, const int* __restrict__ e1p, const int* __restrict__ e2p,
    const float* __restrict__ gt, const float* __restrict__ gtn,
    char* ws, float* __restrict__ out)
{
    int bid = blockIdx.x, tid = threadIdx.x;
    const unsigned long long* MA0 = (const unsigned long long*)(ws + OFF_MA0);
    const unsigned* MA1 = (const unsigned*)(ws + OFF_MA1);
    const unsigned* MB  = (const unsigned*)(ws + OFF_MB);
    float c = 0.0f;
    if (bid < 106) {                                   // chamfer A items (2*13446)
        int idx = bid * 256 + tid;
        if (idx < 26892) {
            int b = idx >= 13446 ? 1 : 0;
            int s = idx - (b ? 13446 : 0);             // s = lvlOff + v
            int v, V; const float* predL; float inv;
            if (s < 642)       { v = s;        V = 642;   predL = p0; inv = 1.f / 1284.f; }
            else if (s < 3204) { v = s - 642;  V = 2562;  predL = p1; inv = 1.f / 5124.f; }
            else               { v = s - 3204; V = 10242; predL = p2; inv = 1.f / 20484.f; }
            float d = b ? funord(MA1[s]) : funord((unsigned)(MA0[s] >> 32));
            const float* pp = predL + ((size_t)(b * V + v)) * 3;
            c = (d + fmaf(pp[0], pp[0], fmaf(pp[1], pp[1], pp[2] * pp[2]))) * inv;
        }
    } else if (bid < 298) {                            // chamfer B items (49152)
        int idx = (bid - 106) * 256 + tid;
        int r = idx & 16383;                           // b*8192+m
        float d = funord(MB[idx]);
        const float* gp = gt + (size_t)r * 3;
        c = (d + fmaf(gp[0], gp[0], fmaf(gp[1], gp[1], gp[2] * gp[2]))) * (1.f / 16384.f);
    } else if (bid == 298) {                           // lap partial sum
        if (tid < 128) c = ((const float*)(ws + OFF_LAP))[tid];
    } else {                                           // edge + normal (80640)
        int idx = (bid - 299) * 256 + tid;
        int E, V, lvlOff, t;
        const float* pred; const int* edges;
        if (idx < 3840)       { E = 1920;  V = 642;   lvlOff = 0;    pred = p0; edges = e0p; t = idx; }
        else if (idx < 19200) { E = 7680;  V = 2562;  lvlOff = 642;  pred = p1; edges = e1p; t = idx - 3840; }
        else                  { E = 30720; V = 10242; lvlOff = 3204; pred = p2; edges = e2p; t = idx - 19200; }
        int b = t / E;
        int e = t % E;
        int a0 = edges[e * 2 + 0];
        int a1 = edges[e * 2 + 1];
        const float* P = pred + (size_t)b * V * 3;
        float dx = P[a0 * 3 + 0] - P[a1 * 3 + 0];
        float dy = P[a0 * 3 + 1] - P[a1 * 3 + 1];
        float dz = P[a0 * 3 + 2] - P[a1 * 3 + 2];
        float sq = fmaf(dx, dx, fmaf(dy, dy, dz * dz));
        float inv = 1.0f / fmaxf(sqrtf(sq), 1e-12f);
        int sel = (int)(unsigned)MA0[lvlOff + a0];     // low 32 bits = b=0 argmin
        const float* nr = gtn + ((size_t)b * 8192 + sel) * 3;
        float nx = nr[0], ny = nr[1], nz = nr[2];
        float invn = 1.0f / fmaxf(sqrtf(fmaf(nx, nx, fmaf(ny, ny, nz * nz))), 1e-12f);
        float dotv = fmaf(dx, nx, fmaf(dy, ny, dz * nz)) * inv * invn;
        float iBE = 1.0f / (2.0f * (float)E);
        c = sq * (0.1f * iBE) + fabsf(dotv) * (0.00016f * iBE);
    }
    c = blockReduceSum256(c);
    if (tid == 0) {
        atomicAdd((float*)ws, c);
        __threadfence();
        unsigned t = atomicAdd((unsigned*)(ws + 4), 1u);
        if (t == gridDim.x - 1) out[0] = atomicAdd((float*)ws, 0.0f);
    }
}

extern "C" void kernel_launch(void* const* d_in, const int* in_sizes, int n_in,
                              void* d_out, int out_size, void* d_ws, size_t ws_size,
                              hipStream_t stream) {
    const float *gt, *gtn, *pred[3], *bef[3];
    const int *edg[3], *lapx[3];
    if (in_sizes[0] == 49152) {
        gt  = (const float*)d_in[0];
        gtn = (const float*)d_in[1];
        for (int i = 0; i < 3; i++) {
            pred[i] = (const float*)d_in[2 + 4 * i];
            bef[i]  = (const float*)d_in[3 + 4 * i];
            edg[i]  = (const int*)  d_in[4 + 4 * i];
            lapx[i] = (const int*)  d_in[5 + 4 * i];
        }
    } else {
        for (int i = 0; i < 3; i++) pred[i] = (const float*)d_in[i];
        for (int i = 0; i < 3; i++) bef[i]  = (const float*)d_in[3 + i];
        gt  = (const float*)d_in[6];
        gtn = (const float*)d_in[7];
        for (int i = 0; i < 3; i++) lapx[i] = (const int*)d_in[8 + i];
        for (int i = 0; i < 3; i++) edg[i]  = (const int*)d_in[11 + i];
    }

    char* ws = (char*)d_ws;
    hipMemsetAsync(ws, 0, 8, stream);                               // acc, ticket
    hipMemsetAsync(ws + OFF_MA0, 0xFF, MINS_END - OFF_MA0, stream); // mins = +inf

    kMega<<<2032, 256, 28672, stream>>>(pred[0], pred[1], pred[2],
                                        bef[0], bef[1], bef[2],
                                        lapx[0], lapx[1], lapx[2], gt, ws);
    kFinal<<<614, 256, 0, stream>>>(pred[0], pred[1], pred[2],
                                    edg[0], edg[1], edg[2], gt, gtn,
                                    ws, (float*)d_out);
}